// Round 1
// baseline (107.324 us; speedup 1.0000x reference)
//
#include <hip/hip_runtime.h>
#include <math.h>

#define B_  2
#define Q_  900
#define CC_ 91
#define T_  64
#define H_  128
#define W_  128
#define HW_ (H_*W_)
#define P_  1024

// ---------------- k1: point metadata + tgt nearest-sample (transposed) ----------------
__global__ __launch_bounds__(256) void k1_prep(
    const float* __restrict__ tgt_masks,   // [B,T,H,W]
    const float* __restrict__ pc,          // [P,2]
    int4*  __restrict__ offs,              // [P] bilinear tap offsets (clipped)
    float4* __restrict__ wts,              // [P] bilinear tap weights (valid-masked)
    float* __restrict__ tgtT,              // [B,P,T]
    float* __restrict__ tsum)              // [B,T]
{
    const int bid = blockIdx.x;            // b*T + t
    const int b = bid / T_, t = bid % T_;
    const int tid = threadIdx.x;
    const int wv = tid >> 6, lane = tid & 63;
    const float* img = tgt_masks + (size_t)(b*T_ + t) * HW_;

    float local = 0.f;
    #pragma unroll
    for (int k = 0; k < P_/256; ++k) {
        int p = tid + k*256;
        float px = pc[2*p], py = pc[2*p+1];
        // grid_sample nearest, align_corners=False: round-half-even (rintf == jnp.round)
        float xf = rintf(px * (float)W_ - 0.5f);
        float yf = rintf(py * (float)H_ - 0.5f);
        bool v = (xf >= 0.f) && (xf < (float)W_) && (yf >= 0.f) && (yf < (float)H_);
        int xc = (int)fminf(fmaxf(xf, 0.f), (float)(W_-1));
        int yc = (int)fminf(fmaxf(yf, 0.f), (float)(H_-1));
        float val = v ? img[yc*W_ + xc] : 0.f;
        tgtT[((size_t)b*P_ + p)*T_ + t] = val;
        local += val;
    }
    // block-reduce local -> tsum[b,t]
    #pragma unroll
    for (int off = 32; off; off >>= 1) local += __shfl_down(local, off);
    __shared__ float sred[4];
    if (lane == 0) sred[wv] = local;
    __syncthreads();
    if (tid == 0) tsum[b*T_ + t] = (sred[0]+sred[1]) + (sred[2]+sred[3]);

    // block 0: bilinear tap metadata (shared by every pred image)
    if (bid == 0) {
        #pragma unroll
        for (int k = 0; k < P_/256; ++k) {
            int p = tid + k*256;
            float px = pc[2*p], py = pc[2*p+1];
            float x = px * (float)W_ - 0.5f;
            float y = py * (float)H_ - 0.5f;
            float x0f = floorf(x), y0f = floorf(y);
            float wx1 = x - x0f, wy1 = y - y0f;
            float wx0 = 1.f - wx1, wy0 = 1.f - wy1;
            int x0 = (int)x0f, y0 = (int)y0f;
            int   xs[2] = {x0, x0+1}, ys[2] = {y0, y0+1};
            float wxs[2] = {wx0, wx1}, wys[2] = {wy0, wy1};
            int o[4]; float ww[4];
            #pragma unroll
            for (int dy = 0; dy < 2; ++dy)
            #pragma unroll
            for (int dx = 0; dx < 2; ++dx) {
                int xi = xs[dx], yi = ys[dy];
                bool v = (xi >= 0) && (xi < W_) && (yi >= 0) && (yi < H_);
                int xcc = min(max(xi, 0), W_-1);
                int ycc = min(max(yi, 0), H_-1);
                o[dy*2+dx]  = ycc*W_ + xcc;
                ww[dy*2+dx] = v ? wys[dy]*wxs[dx] : 0.f;
            }
            offs[p] = make_int4(o[0], o[1], o[2], o[3]);
            wts[p]  = make_float4(ww[0], ww[1], ww[2], ww[3]);
        }
    }
}

// ---------------- k2: main fused cost kernel, one block per (b,q) ----------------
__global__ __launch_bounds__(256) void k2_main(
    const float* __restrict__ pred_logits, // [B,Q,CC]
    const float* __restrict__ pred_boxes,  // [B,Q,4]
    const float* __restrict__ pred_masks,  // [B,Q,H,W]
    const float* __restrict__ tgt_boxes,   // [B,T,4]
    const int*   __restrict__ tgt_labels,  // [B,T]
    const int4*  __restrict__ offs,
    const float4* __restrict__ wts,
    const float* __restrict__ tgtT,        // [B,P,T]
    const float* __restrict__ tsum,        // [B,T]
    float* __restrict__ out)               // [B,Q,T]
{
    __shared__ float pool[HW_];            // 64KB: image, then reused for (pos,neg,s) float4
    __shared__ float sAcc[4][3][T_];
    __shared__ float sSum[2][4];

    const int bid = blockIdx.x;
    const int b = bid / Q_, q = bid % Q_;
    const int tid = threadIdx.x;
    const int wv = tid >> 6, lane = tid & 63;

    // stage image (coalesced float4)
    const float4* img4 = (const float4*)(pred_masks + (size_t)(b*Q_ + q) * HW_);
    float4* pool4 = (float4*)pool;
    #pragma unroll
    for (int k = 0; k < HW_/4/256; ++k)
        pool4[tid + k*256] = img4[tid + k*256];
    __syncthreads();

    // sample 4 points/thread into registers
    float rp[4], rn[4], rs[4];
    float lneg = 0.f, ls = 0.f;
    #pragma unroll
    for (int k = 0; k < P_/256; ++k) {
        int p = tid + k*256;
        int4 o = offs[p]; float4 wt = wts[p];
        float x = wt.x*pool[o.x] + wt.y*pool[o.y] + wt.z*pool[o.z] + wt.w*pool[o.w];
        float e = __expf(-fabsf(x));
        float l = log1pf(e);
        float pos = l + fmaxf(-x, 0.f);   // softplus(-x) = -log_sigmoid(x)
        float neg = l + fmaxf( x, 0.f);   // softplus(x)
        float s = 1.f / (1.f + __expf(-x));
        rp[k] = pos; rn[k] = neg; rs[k] = s;
        lneg += neg; ls += s;
    }
    __syncthreads();   // all image reads done; safe to overwrite pool

    float4* sVals = (float4*)pool;         // [P] (pos,neg,s,_)
    #pragma unroll
    for (int k = 0; k < P_/256; ++k)
        sVals[tid + k*256] = make_float4(rp[k], rn[k], rs[k], 0.f);
    __syncthreads();

    // accumulation: wave wv covers p in [wv*256, wv*256+256), lane = target t
    const float* tb = tgtT + (size_t)b*P_*T_ + lane;
    float accp = 0.f, accn = 0.f, accs = 0.f;
    const int pbase = wv * (P_/4);
    #pragma unroll 8
    for (int pp = 0; pp < P_/4; ++pp) {
        int p = pbase + pp;
        float tv = tb[(size_t)p * T_];
        float4 v = sVals[p];
        accp = fmaf(v.x, tv, accp);
        accn = fmaf(v.y, tv, accn);
        accs = fmaf(v.z, tv, accs);
    }
    sAcc[wv][0][lane] = accp;
    sAcc[wv][1][lane] = accn;
    sAcc[wv][2][lane] = accs;

    // block sums of neg_ce and s
    #pragma unroll
    for (int off = 32; off; off >>= 1) {
        lneg += __shfl_down(lneg, off);
        ls   += __shfl_down(ls, off);
    }
    if (lane == 0) { sSum[0][wv] = lneg; sSum[1][wv] = ls; }
    __syncthreads();

    if (tid < T_) {
        const int t = tid;
        float ap = (sAcc[0][0][t]+sAcc[1][0][t]) + (sAcc[2][0][t]+sAcc[3][0][t]);
        float an = (sAcc[0][1][t]+sAcc[1][1][t]) + (sAcc[2][1][t]+sAcc[3][1][t]);
        float as = (sAcc[0][2][t]+sAcc[1][2][t]) + (sAcc[2][2][t]+sAcc[3][2][t]);
        float sumneg = (sSum[0][0]+sSum[0][1]) + (sSum[0][2]+sSum[0][3]);
        float sums   = (sSum[1][0]+sSum[1][1]) + (sSum[1][2]+sSum[1][3]);

        float ce   = (ap + (sumneg - an)) * (1.f / (float)P_);
        float dice = 1.f - (2.f*as + 1.f) / (sums + tsum[b*T_ + t] + 1.f);

        // focal class cost at target label
        int label = tgt_labels[b*T_ + t];
        float lg = pred_logits[((size_t)(b*Q_ + q))*CC_ + label];
        float e  = __expf(-fabsf(lg));
        float l  = log1pf(e);
        float sp_neg_x = l + fmaxf(-lg, 0.f);  // softplus(-lg)
        float sp_pos_x = l + fmaxf( lg, 0.f);  // softplus(lg)
        float prob = 1.f / (1.f + __expf(-lg));
        float pos_cost = 0.25f * (1.f-prob)*(1.f-prob) * sp_neg_x;
        float neg_cost = 0.75f * prob*prob * sp_pos_x;
        float cclass = pos_cost - neg_cost;

        // bbox L1 + GIoU (cxcywh -> xyxy)
        float4 pb  = *(const float4*)(pred_boxes + (size_t)(b*Q_ + q)*4);
        float4 tbx = *(const float4*)(tgt_boxes + (size_t)(b*T_ + t)*4);
        float cbbox = fabsf(pb.x-tbx.x) + fabsf(pb.y-tbx.y) + fabsf(pb.z-tbx.z) + fabsf(pb.w-tbx.w);

        float px1 = pb.x - 0.5f*pb.z, py1 = pb.y - 0.5f*pb.w;
        float px2 = pb.x + 0.5f*pb.z, py2 = pb.y + 0.5f*pb.w;
        float tx1 = tbx.x - 0.5f*tbx.z, ty1 = tbx.y - 0.5f*tbx.w;
        float tx2 = tbx.x + 0.5f*tbx.z, ty2 = tbx.y + 0.5f*tbx.w;
        float a1 = (px2-px1)*(py2-py1);
        float a2 = (tx2-tx1)*(ty2-ty1);
        float iw = fmaxf(fminf(px2,tx2) - fmaxf(px1,tx1), 0.f);
        float ih = fmaxf(fminf(py2,ty2) - fmaxf(py1,ty1), 0.f);
        float inter = iw*ih;
        float uni = a1 + a2 - inter;
        float iou = inter / uni;
        float cw = fmaxf(fmaxf(px2,tx2) - fminf(px1,tx1), 0.f);
        float ch = fmaxf(fmaxf(py2,ty2) - fminf(py1,ty1), 0.f);
        float ac = cw*ch;
        float giou = iou - (ac - uni)/ac;

        float cost = cbbox + cclass - giou + ce + dice;
        out[((size_t)(b*Q_ + q))*T_ + t] = cost;
    }
}

// ---------------- k3: per-batch max of where(finite, C, 0) ----------------
__global__ __launch_bounds__(256) void k3_max(const float* __restrict__ out,
                                              float* __restrict__ bmax)
{
    const int b = blockIdx.x;
    const float* base = out + (size_t)b * Q_ * T_;
    float m = -INFINITY;
    for (int i = threadIdx.x; i < Q_*T_; i += 256) {
        float v = base[i];
        float c = (fabsf(v) <= 3.402823466e+38f) ? v : 0.f;  // finite? v : 0
        m = fmaxf(m, c);
    }
    #pragma unroll
    for (int off = 32; off; off >>= 1) m = fmaxf(m, __shfl_down(m, off));
    __shared__ float sm[4];
    if ((threadIdx.x & 63) == 0) sm[threadIdx.x >> 6] = m;
    __syncthreads();
    if (threadIdx.x == 0) bmax[b] = fmaxf(fmaxf(sm[0], sm[1]), fmaxf(sm[2], sm[3]));
}

// ---------------- k4: replace non-finite with 2*max ----------------
__global__ __launch_bounds__(256) void k4_fix(float* __restrict__ out,
                                              const float* __restrict__ bmax)
{
    int i = blockIdx.x*256 + threadIdx.x;
    if (i >= B_*Q_*T_) return;
    float v = out[i];
    if (!(fabsf(v) <= 3.402823466e+38f))
        out[i] = 2.f * bmax[i / (Q_*T_)];
}

extern "C" void kernel_launch(void* const* d_in, const int* in_sizes, int n_in,
                              void* d_out, int out_size, void* d_ws, size_t ws_size,
                              hipStream_t stream) {
    const float* pred_logits  = (const float*)d_in[0];
    const float* pred_boxes   = (const float*)d_in[1];
    const float* pred_masks   = (const float*)d_in[2];
    const float* tgt_boxes    = (const float*)d_in[3];
    const float* tgt_masks    = (const float*)d_in[4];
    const float* point_coords = (const float*)d_in[5];
    const int*   tgt_labels   = (const int*)d_in[6];
    float* out = (float*)d_out;

    char* w = (char*)d_ws;
    int4*   offs = (int4*)w;                           // 16 KB
    float4* wts  = (float4*)(w + (16<<10));            // 16 KB
    float*  tgtT = (float*)(w + (32<<10));             // 512 KB
    float*  tsum = (float*)(w + (32<<10) + (size_t)B_*P_*T_*sizeof(float));
    float*  bmax = tsum + B_*T_;

    k1_prep<<<B_*T_, 256, 0, stream>>>(tgt_masks, point_coords, offs, wts, tgtT, tsum);
    k2_main<<<B_*Q_, 256, 0, stream>>>(pred_logits, pred_boxes, pred_masks, tgt_boxes,
                                       tgt_labels, offs, wts, tgtT, tsum, out);
    k3_max<<<B_, 256, 0, stream>>>(out, bmax);
    k4_fix<<<(B_*Q_*T_ + 255)/256, 256, 0, stream>>>(out, bmax);
}

// Round 2
// 88.371 us; speedup vs baseline: 1.2145x; 1.2145x over previous
//
#include <hip/hip_runtime.h>
#include <hip/hip_fp16.h>
#include <math.h>

#define B_  2
#define Q_  900
#define CC_ 91
#define T_  64
#define H_  128
#define W_  128
#define HW_ (H_*W_)
#define P_  1024

// ---------------- k1: point metadata + tgt nearest-sample (pair-transposed) ----------------
// tgtT layout: [B][P/2][T] of float2: element (b,p2,t) = (tgt[2p2][t], tgt[2p2+1][t])
__global__ __launch_bounds__(256) void k1_prep(
    const float* __restrict__ tgt_masks,   // [B,T,H,W]
    const float* __restrict__ pc,          // [P,2]
    int4*  __restrict__ offs,              // [P]
    float4* __restrict__ wts,              // [P]
    float* __restrict__ tgtT,              // [B][P/2][T][2]
    float* __restrict__ tsum)              // [B,T]
{
    const int bid = blockIdx.x;            // b*T + t
    const int b = bid / T_, t = bid % T_;
    const int tid = threadIdx.x;
    const int wv = tid >> 6, lane = tid & 63;
    const float* img = tgt_masks + (size_t)(b*T_ + t) * HW_;

    float local = 0.f;
    #pragma unroll
    for (int k = 0; k < P_/256; ++k) {
        int p = tid + k*256;
        float px = pc[2*p], py = pc[2*p+1];
        float xf = rintf(px * (float)W_ - 0.5f);
        float yf = rintf(py * (float)H_ - 0.5f);
        bool v = (xf >= 0.f) && (xf < (float)W_) && (yf >= 0.f) && (yf < (float)H_);
        int xc = (int)fminf(fmaxf(xf, 0.f), (float)(W_-1));
        int yc = (int)fminf(fmaxf(yf, 0.f), (float)(H_-1));
        float val = v ? img[yc*W_ + xc] : 0.f;
        tgtT[(((size_t)b*(P_/2) + (p>>1))*T_ + t)*2 + (p&1)] = val;
        local += val;
    }
    #pragma unroll
    for (int off = 32; off; off >>= 1) local += __shfl_down(local, off);
    __shared__ float sred[4];
    if (lane == 0) sred[wv] = local;
    __syncthreads();
    if (tid == 0) tsum[b*T_ + t] = (sred[0]+sred[1]) + (sred[2]+sred[3]);

    if (bid == 0) {
        #pragma unroll
        for (int k = 0; k < P_/256; ++k) {
            int p = tid + k*256;
            float px = pc[2*p], py = pc[2*p+1];
            float x = px * (float)W_ - 0.5f;
            float y = py * (float)H_ - 0.5f;
            float x0f = floorf(x), y0f = floorf(y);
            float wx1 = x - x0f, wy1 = y - y0f;
            float wx0 = 1.f - wx1, wy0 = 1.f - wy1;
            int x0 = (int)x0f, y0 = (int)y0f;
            int   xs[2] = {x0, x0+1}, ys[2] = {y0, y0+1};
            float wxs[2] = {wx0, wx1}, wys[2] = {wy0, wy1};
            int o[4]; float ww[4];
            #pragma unroll
            for (int dy = 0; dy < 2; ++dy)
            #pragma unroll
            for (int dx = 0; dx < 2; ++dx) {
                int xi = xs[dx], yi = ys[dy];
                bool v = (xi >= 0) && (xi < W_) && (yi >= 0) && (yi < H_);
                int xcc = min(max(xi, 0), W_-1);
                int ycc = min(max(yi, 0), H_-1);
                o[dy*2+dx]  = ycc*W_ + xcc;
                ww[dy*2+dx] = v ? wys[dy]*wxs[dx] : 0.f;
            }
            offs[p] = make_int4(o[0], o[1], o[2], o[3]);
            wts[p]  = make_float4(ww[0], ww[1], ww[2], ww[3]);
        }
    }
}

// ---------------- k2: main fused cost kernel, one block per (b,q) ----------------
__global__ __launch_bounds__(256) void k2_main(
    const float* __restrict__ pred_logits, // [B,Q,CC]
    const float* __restrict__ pred_boxes,  // [B,Q,4]
    const float* __restrict__ pred_masks,  // [B,Q,H,W]
    const float* __restrict__ tgt_boxes,   // [B,T,4]
    const int*   __restrict__ tgt_labels,  // [B,T]
    const int4*  __restrict__ offs,
    const float4* __restrict__ wts,
    const float* __restrict__ tgtT,        // [B][P/2][T][2]
    const float* __restrict__ tsum,        // [B,T]
    float* __restrict__ out)               // [B,Q,T]
{
    // 32KB: fp16 image, then reused as float2 sVals[P] (8KB)
    __shared__ __align__(16) unsigned char poolraw[HW_*2];
    __shared__ float sAcc[4][2][T_];
    __shared__ float sSum[2][4];

    const int bid = blockIdx.x;
    const int b = bid / Q_, q = bid % Q_;
    const int tid = threadIdx.x;
    const int wv = tid >> 6, lane = tid & 63;

    // stage image as fp16 (coalesced float4 loads, b64 LDS writes)
    __half* pool = (__half*)poolraw;
    {
        const float4* img4 = (const float4*)(pred_masks + (size_t)(b*Q_ + q) * HW_);
        float2* pool2 = (float2*)poolraw;   // one float2 = 4 halfs
        #pragma unroll
        for (int k = 0; k < HW_/4/256; ++k) {
            int g = tid + k*256;
            float4 v = img4[g];
            union { __half2 h2[2]; float2 f2; } u;
            u.h2[0] = __float22half2_rn(make_float2(v.x, v.y));
            u.h2[1] = __float22half2_rn(make_float2(v.z, v.w));
            pool2[g] = u.f2;
        }
    }
    __syncthreads();

    // sample 4 points/thread: keep (x, s) in regs; accumulate softplus(x), s
    float rx[4], rs[4];
    float lneg = 0.f, ls = 0.f;
    #pragma unroll
    for (int k = 0; k < P_/256; ++k) {
        int p = tid + k*256;
        int4 o = offs[p]; float4 wt = wts[p];
        float x = wt.x*__half2float(pool[o.x]) + wt.y*__half2float(pool[o.y])
                + wt.z*__half2float(pool[o.z]) + wt.w*__half2float(pool[o.w]);
        float e = __expf(-fabsf(x));
        float neg = log1pf(e) + fmaxf(x, 0.f);    // softplus(x) = -log_sigmoid(-x)
        float s = 1.f / (1.f + __expf(-x));
        rx[k] = x; rs[k] = s;
        lneg += neg; ls += s;
    }
    __syncthreads();   // all image reads done; safe to overwrite pool

    float2* sVals = (float2*)poolraw;       // [P] (x, s)
    #pragma unroll
    for (int k = 0; k < P_/256; ++k)
        sVals[tid + k*256] = make_float2(rx[k], rs[k]);

    // block sums of neg and s (while LDS writes land)
    #pragma unroll
    for (int off = 32; off; off >>= 1) {
        lneg += __shfl_down(lneg, off);
        ls   += __shfl_down(ls, off);
    }
    if (lane == 0) { sSum[0][wv] = lneg; sSum[1][wv] = ls; }
    __syncthreads();

    // accumulation: wave wv covers pairs p2 in [wv*128, wv*128+128), lane = target t
    const float2* tb = ((const float2*)tgtT) + ((size_t)b*(P_/2))*T_ + lane;
    const float4* sVals4 = (const float4*)poolraw;  // (x0,s0,x1,s1) per pair
    float accx = 0.f, accs = 0.f;
    const int p2base = wv * (P_/8);
    #pragma unroll 8
    for (int i = 0; i < P_/8; ++i) {
        int p2 = p2base + i;
        float2 tv = tb[(size_t)p2 * T_];
        float4 v = sVals4[p2];
        accx = fmaf(v.x, tv.x, accx);
        accx = fmaf(v.z, tv.y, accx);
        accs = fmaf(v.y, tv.x, accs);
        accs = fmaf(v.w, tv.y, accs);
    }
    sAcc[wv][0][lane] = accx;
    sAcc[wv][1][lane] = accs;
    __syncthreads();

    if (tid < T_) {
        const int t = tid;
        float ax = (sAcc[0][0][t]+sAcc[1][0][t]) + (sAcc[2][0][t]+sAcc[3][0][t]);
        float as = (sAcc[0][1][t]+sAcc[1][1][t]) + (sAcc[2][1][t]+sAcc[3][1][t]);
        float sumneg = (sSum[0][0]+sSum[0][1]) + (sSum[0][2]+sSum[0][3]);
        float sums   = (sSum[1][0]+sSum[1][1]) + (sSum[1][2]+sSum[1][3]);

        // CE: pos - neg = -x  =>  ce = (sum(neg) - sum(x*tgt)) / P
        float ce   = (sumneg - ax) * (1.f / (float)P_);
        float dice = 1.f - (2.f*as + 1.f) / (sums + tsum[b*T_ + t] + 1.f);

        int label = tgt_labels[b*T_ + t];
        float lg = pred_logits[((size_t)(b*Q_ + q))*CC_ + label];
        float e  = __expf(-fabsf(lg));
        float l  = log1pf(e);
        float sp_neg_x = l + fmaxf(-lg, 0.f);  // softplus(-lg)
        float sp_pos_x = l + fmaxf( lg, 0.f);  // softplus(lg)
        float prob = 1.f / (1.f + __expf(-lg));
        float pos_cost = 0.25f * (1.f-prob)*(1.f-prob) * sp_neg_x;
        float neg_cost = 0.75f * prob*prob * sp_pos_x;
        float cclass = pos_cost - neg_cost;

        float4 pb  = *(const float4*)(pred_boxes + (size_t)(b*Q_ + q)*4);
        float4 tbx = *(const float4*)(tgt_boxes + (size_t)(b*T_ + t)*4);
        float cbbox = fabsf(pb.x-tbx.x) + fabsf(pb.y-tbx.y) + fabsf(pb.z-tbx.z) + fabsf(pb.w-tbx.w);

        float px1 = pb.x - 0.5f*pb.z, py1 = pb.y - 0.5f*pb.w;
        float px2 = pb.x + 0.5f*pb.z, py2 = pb.y + 0.5f*pb.w;
        float tx1 = tbx.x - 0.5f*tbx.z, ty1 = tbx.y - 0.5f*tbx.w;
        float tx2 = tbx.x + 0.5f*tbx.z, ty2 = tbx.y + 0.5f*tbx.w;
        float a1 = (px2-px1)*(py2-py1);
        float a2 = (tx2-tx1)*(ty2-ty1);
        float iw = fmaxf(fminf(px2,tx2) - fmaxf(px1,tx1), 0.f);
        float ih = fmaxf(fminf(py2,ty2) - fmaxf(py1,ty1), 0.f);
        float inter = iw*ih;
        float uni = a1 + a2 - inter;
        float iou = inter / uni;
        float cw = fmaxf(fmaxf(px2,tx2) - fminf(px1,tx1), 0.f);
        float ch = fmaxf(fmaxf(py2,ty2) - fminf(py1,ty1), 0.f);
        float ac = cw*ch;
        float giou = iou - (ac - uni)/ac;

        float cost = cbbox + cclass - giou + ce + dice;
        out[((size_t)(b*Q_ + q))*T_ + t] = cost;
    }
}

// ---------------- k3: per-batch max of where(finite, C, 0) ----------------
__global__ __launch_bounds__(256) void k3_max(const float* __restrict__ out,
                                              float* __restrict__ bmax)
{
    const int b = blockIdx.x;
    const float* base = out + (size_t)b * Q_ * T_;
    float m = -INFINITY;
    for (int i = threadIdx.x; i < Q_*T_; i += 256) {
        float v = base[i];
        float c = (fabsf(v) <= 3.402823466e+38f) ? v : 0.f;
        m = fmaxf(m, c);
    }
    #pragma unroll
    for (int off = 32; off; off >>= 1) m = fmaxf(m, __shfl_down(m, off));
    __shared__ float sm[4];
    if ((threadIdx.x & 63) == 0) sm[threadIdx.x >> 6] = m;
    __syncthreads();
    if (threadIdx.x == 0) bmax[b] = fmaxf(fmaxf(sm[0], sm[1]), fmaxf(sm[2], sm[3]));
}

// ---------------- k4: replace non-finite with 2*max ----------------
__global__ __launch_bounds__(256) void k4_fix(float* __restrict__ out,
                                              const float* __restrict__ bmax)
{
    int i = blockIdx.x*256 + threadIdx.x;
    if (i >= B_*Q_*T_) return;
    float v = out[i];
    if (!(fabsf(v) <= 3.402823466e+38f))
        out[i] = 2.f * bmax[i / (Q_*T_)];
}

extern "C" void kernel_launch(void* const* d_in, const int* in_sizes, int n_in,
                              void* d_out, int out_size, void* d_ws, size_t ws_size,
                              hipStream_t stream) {
    const float* pred_logits  = (const float*)d_in[0];
    const float* pred_boxes   = (const float*)d_in[1];
    const float* pred_masks   = (const float*)d_in[2];
    const float* tgt_boxes    = (const float*)d_in[3];
    const float* tgt_masks    = (const float*)d_in[4];
    const float* point_coords = (const float*)d_in[5];
    const int*   tgt_labels   = (const int*)d_in[6];
    float* out = (float*)d_out;

    char* w = (char*)d_ws;
    int4*   offs = (int4*)w;                           // 16 KB
    float4* wts  = (float4*)(w + (16<<10));            // 16 KB
    float*  tgtT = (float*)(w + (32<<10));             // 512 KB
    float*  tsum = (float*)(w + (32<<10) + (size_t)B_*P_*T_*sizeof(float));
    float*  bmax = tsum + B_*T_;

    k1_prep<<<B_*T_, 256, 0, stream>>>(tgt_masks, point_coords, offs, wts, tgtT, tsum);
    k2_main<<<B_*Q_, 256, 0, stream>>>(pred_logits, pred_boxes, pred_masks, tgt_boxes,
                                       tgt_labels, offs, wts, tgtT, tsum, out);
    k3_max<<<B_, 256, 0, stream>>>(out, bmax);
    k4_fix<<<(B_*Q_*T_ + 255)/256, 256, 0, stream>>>(out, bmax);
}

// Round 3
// 84.427 us; speedup vs baseline: 1.2712x; 1.0467x over previous
//
#include <hip/hip_runtime.h>
#include <hip/hip_fp16.h>
#include <hip/hip_bf16.h>
#include <math.h>

#define B_    2
#define Q_    900
#define QPAD_ 912      // 57 * 16
#define MT_   57
#define CC_   91
#define T_    64
#define H_    128
#define W_    128
#define HW_   (H_*W_)
#define P_    1024

typedef short short8 __attribute__((ext_vector_type(8)));   // 8 bf16 (4 VGPRs)
typedef float f32x4  __attribute__((ext_vector_type(4)));

static __device__ __forceinline__ unsigned short f2bf(float v) {
    __hip_bfloat16 h = __float2bfloat16(v);   // RN
    return *reinterpret_cast<unsigned short*>(&h);
}

// ---------------- k1: tgt nearest-sample rows [B][T][P] bf16 + tsum + tap metadata ----------------
__global__ __launch_bounds__(256) void k1_prep(
    const float* __restrict__ tgt_masks,   // [B,T,H,W]
    const float* __restrict__ pc,          // [P,2]
    int4*  __restrict__ offs,              // [P]
    float4* __restrict__ wts,              // [P]
    unsigned short* __restrict__ tgtPT,    // [B][T][P] bf16 (K-contiguous = B-frag friendly)
    float* __restrict__ tsum)              // [B,T]
{
    const int bid = blockIdx.x;            // b*T + t
    const int b = bid / T_, t = bid % T_;
    const int tid = threadIdx.x;
    const int wv = tid >> 6, lane = tid & 63;
    const float* img = tgt_masks + (size_t)(b*T_ + t) * HW_;

    float local = 0.f;
    unsigned short pk[4];
    #pragma unroll
    for (int k = 0; k < 4; ++k) {
        int p = tid*4 + k;
        float px = pc[2*p], py = pc[2*p+1];
        // grid_sample nearest, align_corners=False: round half-to-even (rintf == jnp.round)
        float xf = rintf(px * (float)W_ - 0.5f);
        float yf = rintf(py * (float)H_ - 0.5f);
        bool v = (xf >= 0.f) && (xf < (float)W_) && (yf >= 0.f) && (yf < (float)H_);
        int xc = (int)fminf(fmaxf(xf, 0.f), (float)(W_-1));
        int yc = (int)fminf(fmaxf(yf, 0.f), (float)(H_-1));
        float val = v ? img[yc*W_ + xc] : 0.f;
        pk[k] = f2bf(val);
        local += val;
    }
    *(ushort4*)(tgtPT + ((size_t)(b*T_ + t))*P_ + tid*4) =
        make_ushort4(pk[0], pk[1], pk[2], pk[3]);

    #pragma unroll
    for (int off = 32; off; off >>= 1) local += __shfl_down(local, off);
    __shared__ float sred[4];
    if (lane == 0) sred[wv] = local;
    __syncthreads();
    if (tid == 0) tsum[b*T_ + t] = (sred[0]+sred[1]) + (sred[2]+sred[3]);

    // block 0: bilinear tap metadata (shared by every pred image)
    if (bid == 0) {
        #pragma unroll
        for (int k = 0; k < 4; ++k) {
            int p = tid*4 + k;
            float px = pc[2*p], py = pc[2*p+1];
            float x = px * (float)W_ - 0.5f;
            float y = py * (float)H_ - 0.5f;
            float x0f = floorf(x), y0f = floorf(y);
            float wx1 = x - x0f, wy1 = y - y0f;
            float wx0 = 1.f - wx1, wy0 = 1.f - wy1;
            int x0 = (int)x0f, y0 = (int)y0f;
            int   xs2[2] = {x0, x0+1}, ys2[2] = {y0, y0+1};
            float wxs[2] = {wx0, wx1}, wys[2] = {wy0, wy1};
            int o[4]; float ww[4];
            #pragma unroll
            for (int dy = 0; dy < 2; ++dy)
            #pragma unroll
            for (int dx = 0; dx < 2; ++dx) {
                int xi = xs2[dx], yi = ys2[dy];
                bool v = (xi >= 0) && (xi < W_) && (yi >= 0) && (yi < H_);
                int xcc = min(max(xi, 0), W_-1);
                int ycc = min(max(yi, 0), H_-1);
                o[dy*2+dx]  = ycc*W_ + xcc;
                ww[dy*2+dx] = v ? wys[dy]*wxs[dx] : 0.f;
            }
            offs[p] = make_int4(o[0], o[1], o[2], o[3]);
            wts[p]  = make_float4(ww[0], ww[1], ww[2], ww[3]);
        }
    }
}

// ---------------- k2: pure sampler — stage fp16 image, sample, emit bf16 A-rows + row sums ----------------
__global__ __launch_bounds__(256) void k2_sample(
    const float* __restrict__ pred_masks,  // [B,Q,H,W]
    const int4*  __restrict__ offs,
    const float4* __restrict__ wts,
    unsigned short* __restrict__ xsbuf,    // [B][2][QPAD][P] bf16 (ch0 = x, ch1 = s)
    float* __restrict__ lneg,              // [B,Q] sum softplus(x)
    float* __restrict__ lsum)              // [B,Q] sum sigmoid(x)
{
    __shared__ __align__(16) __half pool[HW_];   // 32 KB
    __shared__ float sSum[2][4];

    const int bid = blockIdx.x;
    const int b = bid / Q_, q = bid % Q_;
    const int tid = threadIdx.x;
    const int wv = tid >> 6, lane = tid & 63;

    // stage image as fp16 (coalesced float4 loads)
    {
        const float4* img4 = (const float4*)(pred_masks + (size_t)(b*Q_ + q) * HW_);
        float2* pool2 = (float2*)pool;
        #pragma unroll
        for (int k = 0; k < HW_/4/256; ++k) {
            int g = tid + k*256;
            float4 v = img4[g];
            union { __half2 h2[2]; float2 f2; } u;
            u.h2[0] = __float22half2_rn(make_float2(v.x, v.y));
            u.h2[1] = __float22half2_rn(make_float2(v.z, v.w));
            pool2[g] = u.f2;
        }
    }
    __syncthreads();

    float ln = 0.f, ls = 0.f;
    unsigned short px[4], ps[4];
    #pragma unroll
    for (int k = 0; k < 4; ++k) {
        int p = tid*4 + k;
        int4 o = offs[p]; float4 wt = wts[p];
        float x = wt.x*__half2float(pool[o.x]) + wt.y*__half2float(pool[o.y])
                + wt.z*__half2float(pool[o.z]) + wt.w*__half2float(pool[o.w]);
        float e  = __expf(-fabsf(x));
        float sp = log1pf(e) + fmaxf(x, 0.f);     // softplus(x)
        float r  = 1.f / (1.f + e);
        float s  = (x >= 0.f) ? r : e * r;        // sigmoid(x)
        ln += sp; ls += s;
        px[k] = f2bf(x); ps[k] = f2bf(s);
    }
    // coalesced 8B stores per channel
    *(ushort4*)(xsbuf + ((size_t)(b*2+0)*QPAD_ + q)*P_ + tid*4) = make_ushort4(px[0],px[1],px[2],px[3]);
    *(ushort4*)(xsbuf + ((size_t)(b*2+1)*QPAD_ + q)*P_ + tid*4) = make_ushort4(ps[0],ps[1],ps[2],ps[3]);

    #pragma unroll
    for (int off = 32; off; off >>= 1) {
        ln += __shfl_down(ln, off);
        ls += __shfl_down(ls, off);
    }
    if (lane == 0) { sSum[0][wv] = ln; sSum[1][wv] = ls; }
    __syncthreads();
    if (tid == 0) {
        lneg[b*Q_ + q] = (sSum[0][0]+sSum[0][1]) + (sSum[0][2]+sSum[0][3]);
        lsum[b*Q_ + q] = (sSum[1][0]+sSum[1][1]) + (sSum[1][2]+sSum[1][3]);
    }
}

// ---------------- k3: MFMA GEMM (2 channels share B) + fused cost epilogue ----------------
// one wave per (b, mt): 16 queries x 64 targets
__global__ __launch_bounds__(64) void k3_gemm(
    const unsigned short* __restrict__ xsbuf,  // [B][2][QPAD][P] bf16
    const unsigned short* __restrict__ tgtPT,  // [B][T][P] bf16
    const float* __restrict__ lneg,            // [B,Q]
    const float* __restrict__ lsum,            // [B,Q]
    const float* __restrict__ tsum,            // [B,T]
    const float* __restrict__ pred_logits,     // [B,Q,CC]
    const float* __restrict__ pred_boxes,      // [B,Q,4]
    const float* __restrict__ tgt_boxes,       // [B,T,4]
    const int*   __restrict__ tgt_labels,      // [B,T]
    float* __restrict__ out)                   // [B,Q,T]
{
    const int bid = blockIdx.x;          // b*MT_ + mt
    const int b = bid / MT_, mt = bid % MT_;
    const int l = threadIdx.x;
    const int ml = l & 15, kg = l >> 4;

    // A-frag: lane holds A[m=ml][k = kg*8 + j]; B-frag: lane holds B[k = kg*8 + j][n=ml]
    const short* Ax = (const short*)xsbuf + ((size_t)(b*2+0)*QPAD_ + mt*16 + ml)*P_ + kg*8;
    const short* As = (const short*)xsbuf + ((size_t)(b*2+1)*QPAD_ + mt*16 + ml)*P_ + kg*8;
    const short* Bb = (const short*)tgtPT + ((size_t)(b*T_) + ml)*P_ + kg*8;

    f32x4 accX[4] = {{0,0,0,0},{0,0,0,0},{0,0,0,0},{0,0,0,0}};
    f32x4 accS[4] = {{0,0,0,0},{0,0,0,0},{0,0,0,0},{0,0,0,0}};

    #pragma unroll 4
    for (int kt = 0; kt < 32; ++kt) {
        const int ko = kt * 32;
        short8 afx = *(const short8*)(Ax + ko);
        short8 afs = *(const short8*)(As + ko);
        #pragma unroll
        for (int nt = 0; nt < 4; ++nt) {
            short8 bf = *(const short8*)(Bb + (size_t)nt*16*P_ + ko);
            accX[nt] = __builtin_amdgcn_mfma_f32_16x16x32_bf16(afx, bf, accX[nt], 0, 0, 0);
            accS[nt] = __builtin_amdgcn_mfma_f32_16x16x32_bf16(afs, bf, accS[nt], 0, 0, 0);
        }
    }

    // ---- epilogue: C[row = kg*4 + r][col = ml] ; q = mt*16+row, t = nt*16+ml ----
    // t-side data (4 targets per lane)
    float tsuA[4]; int labA[4]; float4 tbxA[4];
    #pragma unroll
    for (int nt = 0; nt < 4; ++nt) {
        int t = nt*16 + ml;
        tsuA[nt] = tsum[b*T_ + t];
        labA[nt] = tgt_labels[b*T_ + t];
        tbxA[nt] = *(const float4*)(tgt_boxes + (size_t)(b*T_ + t)*4);
    }

    #pragma unroll
    for (int r = 0; r < 4; ++r) {
        int q = mt*16 + kg*4 + r;
        int qc = min(q, Q_-1);
        float ln  = lneg[b*Q_ + qc];
        float lsv = lsum[b*Q_ + qc];
        float4 pb = *(const float4*)(pred_boxes + (size_t)(b*Q_ + qc)*4);
        const float* lgrow = pred_logits + ((size_t)(b*Q_ + qc))*CC_;

        float px1 = pb.x - 0.5f*pb.z, py1 = pb.y - 0.5f*pb.w;
        float px2 = pb.x + 0.5f*pb.z, py2 = pb.y + 0.5f*pb.w;
        float a1 = (px2-px1)*(py2-py1);

        #pragma unroll
        for (int nt = 0; nt < 4; ++nt) {
            int t = nt*16 + ml;
            float axv = accX[nt][r], asv = accS[nt][r];
            float ce   = (ln - axv) * (1.f/(float)P_);
            float dice = 1.f - (2.f*asv + 1.f) / (lsv + tsuA[nt] + 1.f);

            float lg = lgrow[labA[nt]];
            float e  = __expf(-fabsf(lg));
            float lp = log1pf(e);
            float sp_neg = lp + fmaxf(-lg, 0.f);
            float sp_pos = lp + fmaxf( lg, 0.f);
            float prob = 1.f / (1.f + __expf(-lg));
            float cclass = 0.25f*(1.f-prob)*(1.f-prob)*sp_neg - 0.75f*prob*prob*sp_pos;

            float4 tbx = tbxA[nt];
            float cbbox = fabsf(pb.x-tbx.x) + fabsf(pb.y-tbx.y) + fabsf(pb.z-tbx.z) + fabsf(pb.w-tbx.w);
            float tx1 = tbx.x - 0.5f*tbx.z, ty1 = tbx.y - 0.5f*tbx.w;
            float tx2 = tbx.x + 0.5f*tbx.z, ty2 = tbx.y + 0.5f*tbx.w;
            float a2 = (tx2-tx1)*(ty2-ty1);
            float iw = fmaxf(fminf(px2,tx2) - fmaxf(px1,tx1), 0.f);
            float ih = fmaxf(fminf(py2,ty2) - fmaxf(py1,ty1), 0.f);
            float inter = iw*ih;
            float uni = a1 + a2 - inter;
            float iou = inter / uni;
            float cw = fmaxf(fmaxf(px2,tx2) - fminf(px1,tx1), 0.f);
            float ch = fmaxf(fmaxf(py2,ty2) - fminf(py1,ty1), 0.f);
            float ac = cw*ch;
            float giou = iou - (ac - uni)/ac;

            if (q < Q_)
                out[((size_t)(b*Q_ + q))*T_ + t] = cbbox + cclass - giou + ce + dice;
        }
    }
}

// ---------------- k4: per-batch max of where(finite, C, 0) ----------------
__global__ __launch_bounds__(256) void k4_max(const float* __restrict__ out,
                                              float* __restrict__ bmax)
{
    const int b = blockIdx.x;
    const float* base = out + (size_t)b * Q_ * T_;
    float m = -INFINITY;
    for (int i = threadIdx.x; i < Q_*T_; i += 256) {
        float v = base[i];
        float c = (fabsf(v) <= 3.402823466e+38f) ? v : 0.f;
        m = fmaxf(m, c);
    }
    #pragma unroll
    for (int off = 32; off; off >>= 1) m = fmaxf(m, __shfl_down(m, off));
    __shared__ float sm[4];
    if ((threadIdx.x & 63) == 0) sm[threadIdx.x >> 6] = m;
    __syncthreads();
    if (threadIdx.x == 0) bmax[b] = fmaxf(fmaxf(sm[0], sm[1]), fmaxf(sm[2], sm[3]));
}

// ---------------- k5: replace non-finite with 2*max ----------------
__global__ __launch_bounds__(256) void k5_fix(float* __restrict__ out,
                                              const float* __restrict__ bmax)
{
    int i = blockIdx.x*256 + threadIdx.x;
    if (i >= B_*Q_*T_) return;
    float v = out[i];
    if (!(fabsf(v) <= 3.402823466e+38f))
        out[i] = 2.f * bmax[i / (Q_*T_)];
}

extern "C" void kernel_launch(void* const* d_in, const int* in_sizes, int n_in,
                              void* d_out, int out_size, void* d_ws, size_t ws_size,
                              hipStream_t stream) {
    const float* pred_logits  = (const float*)d_in[0];
    const float* pred_boxes   = (const float*)d_in[1];
    const float* pred_masks   = (const float*)d_in[2];
    const float* tgt_boxes    = (const float*)d_in[3];
    const float* tgt_masks    = (const float*)d_in[4];
    const float* point_coords = (const float*)d_in[5];
    const int*   tgt_labels   = (const int*)d_in[6];
    float* out = (float*)d_out;

    // workspace layout (16B-aligned offsets), total ~7.8 MB
    char* w = (char*)d_ws;
    int4*           offs  = (int4*)w;                                   // 16 KB
    float4*         wts   = (float4*)(w + 16384);                       // 16 KB
    unsigned short* tgtPT = (unsigned short*)(w + 32768);               // 256 KB
    unsigned short* xsbuf = (unsigned short*)(w + 32768 + 262144);      // 7.29 MB
    size_t xs_bytes = (size_t)B_*2*QPAD_*P_*2;
    char* w2 = w + 32768 + 262144 + xs_bytes;
    float* tsum = (float*)w2;                    // 512 B
    float* lneg = (float*)(w2 + 512);            // 7200 B
    float* lsum = (float*)(w2 + 512 + 7296);     // 7200 B (7296 keeps 16B alignment)
    float* bmax = (float*)(w2 + 512 + 2*7296);

    k1_prep<<<B_*T_, 256, 0, stream>>>(tgt_masks, point_coords, offs, wts, tgtPT, tsum);
    k2_sample<<<B_*Q_, 256, 0, stream>>>(pred_masks, offs, wts, xsbuf, lneg, lsum);
    k3_gemm<<<B_*MT_, 64, 0, stream>>>(xsbuf, tgtPT, lneg, lsum, tsum,
                                       pred_logits, pred_boxes, tgt_boxes, tgt_labels, out);
    k4_max<<<B_, 256, 0, stream>>>(out, bmax);
    k5_fix<<<(B_*Q_*T_ + 255)/256, 256, 0, stream>>>(out, bmax);
}

// Round 4
// 82.922 us; speedup vs baseline: 1.2943x; 1.0181x over previous
//
#include <hip/hip_runtime.h>
#include <hip/hip_bf16.h>
#include <math.h>

#define B_    2
#define Q_    900
#define QPAD_ 912      // 57 * 16
#define MT_   57
#define CC_   91
#define T_    64
#define H_    128
#define W_    128
#define HW_   (H_*W_)
#define P_    1024
#define FLT_BIG 3.402823466e+38f

typedef short short8 __attribute__((ext_vector_type(8)));   // 8 bf16 (4 VGPRs)
typedef float f32x4  __attribute__((ext_vector_type(4)));

static __device__ __forceinline__ unsigned short f2bf(float v) {
    __hip_bfloat16 h = __float2bfloat16(v);   // RN
    return *reinterpret_cast<unsigned short*>(&h);
}

// ---------------- k1: tgt nearest-sample rows [B][T][P] bf16 + tsum + tap metadata ----------------
__global__ __launch_bounds__(256) void k1_prep(
    const float* __restrict__ tgt_masks,   // [B,T,H,W]
    const float* __restrict__ pc,          // [P,2]
    int4*  __restrict__ offs,              // [P]
    float4* __restrict__ wts,              // [P]
    unsigned short* __restrict__ tgtPT,    // [B][T][P] bf16 (K-contiguous)
    float* __restrict__ tsum,              // [B,T]
    float* __restrict__ bmax)              // [B] (re-zeroed every call)
{
    const int bid = blockIdx.x;            // b*T + t
    const int b = bid / T_, t = bid % T_;
    const int tid = threadIdx.x;
    const int wv = tid >> 6, lane = tid & 63;
    const float* img = tgt_masks + (size_t)(b*T_ + t) * HW_;

    if (bid == 0 && tid < B_) bmax[tid] = 0.f;

    float local = 0.f;
    unsigned short pk[4];
    #pragma unroll
    for (int k = 0; k < 4; ++k) {
        int p = tid*4 + k;
        float px = pc[2*p], py = pc[2*p+1];
        // grid_sample nearest, align_corners=False: round half-to-even (rintf == jnp.round)
        float xf = rintf(px * (float)W_ - 0.5f);
        float yf = rintf(py * (float)H_ - 0.5f);
        bool v = (xf >= 0.f) && (xf < (float)W_) && (yf >= 0.f) && (yf < (float)H_);
        int xc = (int)fminf(fmaxf(xf, 0.f), (float)(W_-1));
        int yc = (int)fminf(fmaxf(yf, 0.f), (float)(H_-1));
        float val = v ? img[yc*W_ + xc] : 0.f;
        pk[k] = f2bf(val);
        local += val;
    }
    *(ushort4*)(tgtPT + ((size_t)(b*T_ + t))*P_ + tid*4) =
        make_ushort4(pk[0], pk[1], pk[2], pk[3]);

    #pragma unroll
    for (int off = 32; off; off >>= 1) local += __shfl_down(local, off);
    __shared__ float sred[4];
    if (lane == 0) sred[wv] = local;
    __syncthreads();
    if (tid == 0) tsum[b*T_ + t] = (sred[0]+sred[1]) + (sred[2]+sred[3]);

    // block 0: bilinear tap metadata (shared by every pred image)
    if (bid == 0) {
        #pragma unroll
        for (int k = 0; k < 4; ++k) {
            int p = tid*4 + k;
            float px = pc[2*p], py = pc[2*p+1];
            float x = px * (float)W_ - 0.5f;
            float y = py * (float)H_ - 0.5f;
            float x0f = floorf(x), y0f = floorf(y);
            float wx1 = x - x0f, wy1 = y - y0f;
            float wx0 = 1.f - wx1, wy0 = 1.f - wy1;
            int x0 = (int)x0f, y0 = (int)y0f;
            int   xs2[2] = {x0, x0+1}, ys2[2] = {y0, y0+1};
            float wxs[2] = {wx0, wx1}, wys[2] = {wy0, wy1};
            int o[4]; float ww[4];
            #pragma unroll
            for (int dy = 0; dy < 2; ++dy)
            #pragma unroll
            for (int dx = 0; dx < 2; ++dx) {
                int xi = xs2[dx], yi = ys2[dy];
                bool v = (xi >= 0) && (xi < W_) && (yi >= 0) && (yi < H_);
                int xcc = min(max(xi, 0), W_-1);
                int ycc = min(max(yi, 0), H_-1);
                o[dy*2+dx]  = ycc*W_ + xcc;
                ww[dy*2+dx] = v ? wys[dy]*wxs[dx] : 0.f;
            }
            offs[p] = make_int4(o[0], o[1], o[2], o[3]);
            wts[p]  = make_float4(ww[0], ww[1], ww[2], ww[3]);
        }
    }
}

// ---------------- k2: direct-gather sampler — no LDS, no barriers, one wave per q ----------------
__global__ __launch_bounds__(256) void k2_sample(
    const float* __restrict__ pred_masks,  // [B,Q,H,W]
    const int4*  __restrict__ offs,
    const float4* __restrict__ wts,
    unsigned short* __restrict__ xsbuf,    // [B][2][QPAD][P] bf16 (ch0 = x, ch1 = s)
    float* __restrict__ lneg,              // [B,Q] sum softplus(x)
    float* __restrict__ lsum)              // [B,Q] sum sigmoid(x)
{
    const int wv = threadIdx.x >> 6, lane = threadIdx.x & 63;
    const int bq = blockIdx.x * 4 + wv;    // 450*4 = 1800 = B_*Q_
    const int b = bq / Q_, q = bq % Q_;
    const float* __restrict__ img = pred_masks + (size_t)bq * HW_;

    float ln = 0.f, ls = 0.f;
    union PK { unsigned short u[16]; int4 v[2]; };
    PK px, ps;

    #pragma unroll
    for (int j = 0; j < 16; ++j) {
        int p = lane*16 + j;               // linear p: lane owns 32B chunk -> fat stores
        int4 o = offs[p]; float4 wt = wts[p];
        float x = wt.x*img[o.x] + wt.y*img[o.y] + wt.z*img[o.z] + wt.w*img[o.w];
        float e  = __expf(-fabsf(x));
        float sp = log1pf(e) + fmaxf(x, 0.f);     // softplus(x)
        float r  = 1.f / (1.f + e);
        float s  = (x >= 0.f) ? r : e * r;        // sigmoid(x)
        ln += sp; ls += s;
        px.u[j] = f2bf(x); ps.u[j] = f2bf(s);
    }

    unsigned short* rx = xsbuf + ((size_t)(b*2+0)*QPAD_ + q)*P_ + lane*16;
    unsigned short* rs = xsbuf + ((size_t)(b*2+1)*QPAD_ + q)*P_ + lane*16;
    *(int4*)rx       = px.v[0];
    *(int4*)(rx + 8) = px.v[1];
    *(int4*)rs       = ps.v[0];
    *(int4*)(rs + 8) = ps.v[1];

    #pragma unroll
    for (int off = 32; off; off >>= 1) {
        ln += __shfl_down(ln, off);
        ls += __shfl_down(ls, off);
    }
    if (lane == 0) {
        lneg[b*Q_ + q] = ln;
        lsum[b*Q_ + q] = ls;
    }
}

// ---------------- k3: MFMA GEMM, K split across 4 waves + LDS reduce + fused epilogue ----------------
__global__ __launch_bounds__(256) void k3_gemm(
    const unsigned short* __restrict__ xsbuf,  // [B][2][QPAD][P] bf16
    const unsigned short* __restrict__ tgtPT,  // [B][T][P] bf16
    const float* __restrict__ lneg,            // [B,Q]
    const float* __restrict__ lsum,            // [B,Q]
    const float* __restrict__ tsum,            // [B,T]
    const float* __restrict__ pred_logits,     // [B,Q,CC]
    const float* __restrict__ pred_boxes,      // [B,Q,4]
    const float* __restrict__ tgt_boxes,       // [B,T,4]
    const int*   __restrict__ tgt_labels,      // [B,T]
    float* __restrict__ out)                   // [B,Q,T]
{
    __shared__ f32x4 sAcc[4][64][8];     // 32 KB

    const int bid = blockIdx.x;          // b*MT_ + mt
    const int b = bid / MT_, mt = bid % MT_;
    const int w = threadIdx.x >> 6, l = threadIdx.x & 63;
    const int ml = l & 15, kg = l >> 4;

    // wave w covers k in [w*256, (w+1)*256)
    const short* Ax = (const short*)xsbuf + ((size_t)(b*2+0)*QPAD_ + mt*16 + ml)*P_ + kg*8 + w*256;
    const short* As = (const short*)xsbuf + ((size_t)(b*2+1)*QPAD_ + mt*16 + ml)*P_ + kg*8 + w*256;
    const short* Bb = (const short*)tgtPT + ((size_t)(b*T_) + ml)*P_ + kg*8 + w*256;

    f32x4 accX[4] = {{0,0,0,0},{0,0,0,0},{0,0,0,0},{0,0,0,0}};
    f32x4 accS[4] = {{0,0,0,0},{0,0,0,0},{0,0,0,0},{0,0,0,0}};

    #pragma unroll
    for (int kt = 0; kt < 8; ++kt) {
        const int ko = kt * 32;
        short8 afx = *(const short8*)(Ax + ko);
        short8 afs = *(const short8*)(As + ko);
        #pragma unroll
        for (int nt = 0; nt < 4; ++nt) {
            short8 bf = *(const short8*)(Bb + (size_t)nt*16*P_ + ko);
            accX[nt] = __builtin_amdgcn_mfma_f32_16x16x32_bf16(afx, bf, accX[nt], 0, 0, 0);
            accS[nt] = __builtin_amdgcn_mfma_f32_16x16x32_bf16(afs, bf, accS[nt], 0, 0, 0);
        }
    }

    #pragma unroll
    for (int nt = 0; nt < 4; ++nt) {
        sAcc[w][l][nt*2+0] = accX[nt];
        sAcc[w][l][nt*2+1] = accS[nt];
    }
    __syncthreads();

    // wave w handles epilogue for nt = w (t = w*16 + ml)
    f32x4 aX = sAcc[0][l][w*2+0];
    f32x4 aS = sAcc[0][l][w*2+1];
    #pragma unroll
    for (int w2 = 1; w2 < 4; ++w2) {
        aX += sAcc[w2][l][w*2+0];
        aS += sAcc[w2][l][w*2+1];
    }

    const int t = w*16 + ml;
    const float tsu = tsum[b*T_ + t];
    const int   lab = tgt_labels[b*T_ + t];
    const float4 tbx = *(const float4*)(tgt_boxes + (size_t)(b*T_ + t)*4);
    float tx1 = tbx.x - 0.5f*tbx.z, ty1 = tbx.y - 0.5f*tbx.w;
    float tx2 = tbx.x + 0.5f*tbx.z, ty2 = tbx.y + 0.5f*tbx.w;
    float a2 = (tx2-tx1)*(ty2-ty1);

    #pragma unroll
    for (int r = 0; r < 4; ++r) {
        int q = mt*16 + kg*4 + r;
        int qc = min(q, Q_-1);
        float ln  = lneg[b*Q_ + qc];
        float lsv = lsum[b*Q_ + qc];
        float4 pb = *(const float4*)(pred_boxes + (size_t)(b*Q_ + qc)*4);
        float lg = pred_logits[((size_t)(b*Q_ + qc))*CC_ + lab];

        float ce   = (ln - aX[r]) * (1.f/(float)P_);
        float dice = 1.f - (2.f*aS[r] + 1.f) / (lsv + tsu + 1.f);

        float e  = __expf(-fabsf(lg));
        float lp = log1pf(e);
        float sp_neg = lp + fmaxf(-lg, 0.f);
        float sp_pos = lp + fmaxf( lg, 0.f);
        float prob = 1.f / (1.f + __expf(-lg));
        float cclass = 0.25f*(1.f-prob)*(1.f-prob)*sp_neg - 0.75f*prob*prob*sp_pos;

        float cbbox = fabsf(pb.x-tbx.x) + fabsf(pb.y-tbx.y) + fabsf(pb.z-tbx.z) + fabsf(pb.w-tbx.w);
        float px1 = pb.x - 0.5f*pb.z, py1 = pb.y - 0.5f*pb.w;
        float px2 = pb.x + 0.5f*pb.z, py2 = pb.y + 0.5f*pb.w;
        float a1 = (px2-px1)*(py2-py1);
        float iw = fmaxf(fminf(px2,tx2) - fmaxf(px1,tx1), 0.f);
        float ih = fmaxf(fminf(py2,ty2) - fmaxf(py1,ty1), 0.f);
        float inter = iw*ih;
        float uni = a1 + a2 - inter;
        float iou = inter / uni;
        float cw = fmaxf(fmaxf(px2,tx2) - fminf(px1,tx1), 0.f);
        float ch = fmaxf(fmaxf(py2,ty2) - fminf(py1,ty1), 0.f);
        float ac = cw*ch;
        float giou = iou - (ac - uni)/ac;

        if (q < Q_)
            out[((size_t)(b*Q_ + q))*T_ + t] = cbbox + cclass - giou + ce + dice;
    }
}

// ---------------- k4: per-batch max of where(finite, C, 0), 64 blocks/batch + atomicMax ----------------
__global__ __launch_bounds__(256) void k4_max(const float* __restrict__ out,
                                              float* __restrict__ bmax)
{
    const int b   = blockIdx.x >> 6;     // 64 blocks per batch
    const int blk = blockIdx.x & 63;
    const float* base = out + (size_t)b * Q_ * T_;
    float m = 0.f;                        // clamp at 0: max only matters when a non-finite exists,
                                          // in which case reference candidates include 0 as well
    for (int i = blk*256 + threadIdx.x; i < Q_*T_; i += 64*256) {
        float v = base[i];
        float c = (fabsf(v) <= FLT_BIG) ? v : 0.f;
        m = fmaxf(m, c);
    }
    #pragma unroll
    for (int off = 32; off; off >>= 1) m = fmaxf(m, __shfl_down(m, off));
    __shared__ float sm[4];
    if ((threadIdx.x & 63) == 0) sm[threadIdx.x >> 6] = m;
    __syncthreads();
    if (threadIdx.x == 0) {
        float bm = fmaxf(fmaxf(sm[0], sm[1]), fmaxf(sm[2], sm[3]));
        atomicMax((unsigned int*)&bmax[b], __float_as_uint(bm));  // bm >= 0: uint order == float order
    }
}

// ---------------- k5: replace non-finite with 2*max ----------------
__global__ __launch_bounds__(256) void k5_fix(float* __restrict__ out,
                                              const float* __restrict__ bmax)
{
    int i = blockIdx.x*256 + threadIdx.x;
    if (i >= B_*Q_*T_) return;
    float v = out[i];
    if (!(fabsf(v) <= FLT_BIG))
        out[i] = 2.f * bmax[i / (Q_*T_)];
}

extern "C" void kernel_launch(void* const* d_in, const int* in_sizes, int n_in,
                              void* d_out, int out_size, void* d_ws, size_t ws_size,
                              hipStream_t stream) {
    const float* pred_logits  = (const float*)d_in[0];
    const float* pred_boxes   = (const float*)d_in[1];
    const float* pred_masks   = (const float*)d_in[2];
    const float* tgt_boxes    = (const float*)d_in[3];
    const float* tgt_masks    = (const float*)d_in[4];
    const float* point_coords = (const float*)d_in[5];
    const int*   tgt_labels   = (const int*)d_in[6];
    float* out = (float*)d_out;

    // workspace layout (16B-aligned), total ~7.8 MB
    char* w = (char*)d_ws;
    int4*           offs  = (int4*)w;                                   // 16 KB
    float4*         wts   = (float4*)(w + 16384);                       // 16 KB
    unsigned short* tgtPT = (unsigned short*)(w + 32768);               // 256 KB
    unsigned short* xsbuf = (unsigned short*)(w + 32768 + 262144);      // 7.29 MB
    size_t xs_bytes = (size_t)B_*2*QPAD_*P_*2;
    char* w2 = w + 32768 + 262144 + xs_bytes;
    float* tsum = (float*)w2;                    // 512 B
    float* lneg = (float*)(w2 + 512);            // 7200 B (pad to 7296)
    float* lsum = (float*)(w2 + 512 + 7296);     // 7200 B
    float* bmax = (float*)(w2 + 512 + 2*7296);

    k1_prep<<<B_*T_, 256, 0, stream>>>(tgt_masks, point_coords, offs, wts, tgtPT, tsum, bmax);
    k2_sample<<<(B_*Q_)/4, 256, 0, stream>>>(pred_masks, offs, wts, xsbuf, lneg, lsum);
    k3_gemm<<<B_*MT_, 256, 0, stream>>>(xsbuf, tgtPT, lneg, lsum, tsum,
                                        pred_logits, pred_boxes, tgt_boxes, tgt_labels, out);
    k4_max<<<B_*64, 256, 0, stream>>>(out, bmax);
    k5_fix<<<(B_*Q_*T_ + 255)/256, 256, 0, stream>>>(out, bmax);
}

// Round 5
// 54.715 us; speedup vs baseline: 1.9615x; 1.5155x over previous
//
#include <hip/hip_runtime.h>
#include <hip/hip_bf16.h>
#include <math.h>

#define B_    2
#define Q_    900
#define QPAD_ 912      // 57 * 16
#define MT_   57
#define CC_   91
#define T_    64
#define H_    128
#define W_    128
#define HW_   (H_*W_)
#define P_    1024
#define FLT_BIG 3.402823466e+38f

typedef short short8 __attribute__((ext_vector_type(8)));   // 8 bf16 (4 VGPRs)
typedef float f32x4  __attribute__((ext_vector_type(4)));

static __device__ __forceinline__ unsigned short f2bf(float v) {
    __hip_bfloat16 h = __float2bfloat16(v);   // RN
    return *reinterpret_cast<unsigned short*>(&h);
}

// ---------------- k1: tgt nearest-sample rows [B][T][P] bf16 + tsum + tap metadata ----------------
__global__ __launch_bounds__(256) void k1_prep(
    const float* __restrict__ tgt_masks,   // [B,T,H,W]
    const float* __restrict__ pc,          // [P,2]
    int4*  __restrict__ offs,              // [P]
    float4* __restrict__ wts,              // [P]
    unsigned short* __restrict__ tgtPT,    // [B][T][P] bf16 (K-contiguous)
    float* __restrict__ tsum,              // [B,T]
    float* __restrict__ bmax)              // [B] (re-zeroed every call)
{
    const int bid = blockIdx.x;            // b*T + t
    const int b = bid / T_, t = bid % T_;
    const int tid = threadIdx.x;
    const int wv = tid >> 6, lane = tid & 63;
    const float* img = tgt_masks + (size_t)(b*T_ + t) * HW_;

    if (bid == 0 && tid < B_) bmax[tid] = 0.f;

    float local = 0.f;
    unsigned short pk[4];
    #pragma unroll
    for (int k = 0; k < 4; ++k) {
        int p = tid*4 + k;
        float px = pc[2*p], py = pc[2*p+1];
        // grid_sample nearest, align_corners=False: round half-to-even (rintf == jnp.round)
        float xf = rintf(px * (float)W_ - 0.5f);
        float yf = rintf(py * (float)H_ - 0.5f);
        bool v = (xf >= 0.f) && (xf < (float)W_) && (yf >= 0.f) && (yf < (float)H_);
        int xc = (int)fminf(fmaxf(xf, 0.f), (float)(W_-1));
        int yc = (int)fminf(fmaxf(yf, 0.f), (float)(H_-1));
        float val = v ? img[yc*W_ + xc] : 0.f;
        pk[k] = f2bf(val);
        local += val;
    }
    *(ushort4*)(tgtPT + ((size_t)(b*T_ + t))*P_ + tid*4) =
        make_ushort4(pk[0], pk[1], pk[2], pk[3]);

    #pragma unroll
    for (int off = 32; off; off >>= 1) local += __shfl_down(local, off);
    __shared__ float sred[4];
    if (lane == 0) sred[wv] = local;
    __syncthreads();
    if (tid == 0) tsum[b*T_ + t] = (sred[0]+sred[1]) + (sred[2]+sred[3]);

    // block 0: bilinear tap metadata (shared by every pred image)
    if (bid == 0) {
        #pragma unroll
        for (int k = 0; k < 4; ++k) {
            int p = tid*4 + k;
            float px = pc[2*p], py = pc[2*p+1];
            float x = px * (float)W_ - 0.5f;
            float y = py * (float)H_ - 0.5f;
            float x0f = floorf(x), y0f = floorf(y);
            float wx1 = x - x0f, wy1 = y - y0f;
            float wx0 = 1.f - wx1, wy0 = 1.f - wy1;
            int x0 = (int)x0f, y0 = (int)y0f;
            int   xs2[2] = {x0, x0+1}, ys2[2] = {y0, y0+1};
            float wxs[2] = {wx0, wx1}, wys[2] = {wy0, wy1};
            int o[4]; float ww[4];
            #pragma unroll
            for (int dy = 0; dy < 2; ++dy)
            #pragma unroll
            for (int dx = 0; dx < 2; ++dx) {
                int xi = xs2[dx], yi = ys2[dy];
                bool v = (xi >= 0) && (xi < W_) && (yi >= 0) && (yi < H_);
                int xcc = min(max(xi, 0), W_-1);
                int ycc = min(max(yi, 0), H_-1);
                o[dy*2+dx]  = ycc*W_ + xcc;
                ww[dy*2+dx] = v ? wys[dy]*wxs[dx] : 0.f;
            }
            offs[p] = make_int4(o[0], o[1], o[2], o[3]);
            wts[p]  = make_float4(ww[0], ww[1], ww[2], ww[3]);
        }
    }
}

// ---------------- k2: direct-gather sampler — 1800 blocks, 4 points/thread, no LDS image ----------------
__global__ __launch_bounds__(256) void k2_sample(
    const float* __restrict__ pred_masks,  // [B,Q,H,W]
    const int4*  __restrict__ offs,
    const float4* __restrict__ wts,
    unsigned short* __restrict__ xsbuf,    // [B][2][QPAD][P] bf16 (ch0 = x, ch1 = s)
    float* __restrict__ lneg,              // [B,Q] sum softplus(x)
    float* __restrict__ lsum)              // [B,Q] sum sigmoid(x)
{
    const int bq = blockIdx.x;             // b*Q + q
    const int b = bq / Q_, q = bq % Q_;
    const int tid = threadIdx.x;
    const int wv = tid >> 6, lane = tid & 63;
    const float* __restrict__ img = pred_masks + (size_t)bq * HW_;

    // gather 16 taps for 4 points (all independent -> deep MLP)
    float xv[4];
    {
        float tap[4][4];
        int4  o4[4]; float4 w4[4];
        #pragma unroll
        for (int k = 0; k < 4; ++k) { o4[k] = offs[tid*4 + k]; w4[k] = wts[tid*4 + k]; }
        #pragma unroll
        for (int k = 0; k < 4; ++k) {
            tap[k][0] = img[o4[k].x]; tap[k][1] = img[o4[k].y];
            tap[k][2] = img[o4[k].z]; tap[k][3] = img[o4[k].w];
        }
        #pragma unroll
        for (int k = 0; k < 4; ++k)
            xv[k] = w4[k].x*tap[k][0] + w4[k].y*tap[k][1] + w4[k].z*tap[k][2] + w4[k].w*tap[k][3];
    }

    float ln = 0.f, ls = 0.f;
    unsigned short px[4], ps[4];
    #pragma unroll
    for (int k = 0; k < 4; ++k) {
        float x = xv[k];
        float e  = __expf(-fabsf(x));
        float sp = __logf(1.f + e) + fmaxf(x, 0.f);   // softplus(x); |err| <= ~1e-7 abs
        float r  = 1.f / (1.f + e);
        float s  = (x >= 0.f) ? r : e * r;            // sigmoid(x)
        ln += sp; ls += s;
        px[k] = f2bf(x); ps[k] = f2bf(s);
    }

    *(ushort4*)(xsbuf + ((size_t)(b*2+0)*QPAD_ + q)*P_ + tid*4) = make_ushort4(px[0],px[1],px[2],px[3]);
    *(ushort4*)(xsbuf + ((size_t)(b*2+1)*QPAD_ + q)*P_ + tid*4) = make_ushort4(ps[0],ps[1],ps[2],ps[3]);

    #pragma unroll
    for (int off = 32; off; off >>= 1) {
        ln += __shfl_down(ln, off);
        ls += __shfl_down(ls, off);
    }
    __shared__ float sSum[2][4];
    if (lane == 0) { sSum[0][wv] = ln; sSum[1][wv] = ls; }
    __syncthreads();
    if (tid == 0) {
        lneg[b*Q_ + q] = (sSum[0][0]+sSum[0][1]) + (sSum[0][2]+sSum[0][3]);
        lsum[b*Q_ + q] = (sSum[1][0]+sSum[1][1]) + (sSum[1][2]+sSum[1][3]);
    }
}

// ---------------- k3: MFMA GEMM, K split across 4 waves + LDS reduce + fused epilogue ----------------
__global__ __launch_bounds__(256) void k3_gemm(
    const unsigned short* __restrict__ xsbuf,  // [B][2][QPAD][P] bf16
    const unsigned short* __restrict__ tgtPT,  // [B][T][P] bf16
    const float* __restrict__ lneg,            // [B,Q]
    const float* __restrict__ lsum,            // [B,Q]
    const float* __restrict__ tsum,            // [B,T]
    const float* __restrict__ pred_logits,     // [B,Q,CC]
    const float* __restrict__ pred_boxes,      // [B,Q,4]
    const float* __restrict__ tgt_boxes,       // [B,T,4]
    const int*   __restrict__ tgt_labels,      // [B,T]
    float* __restrict__ out)                   // [B,Q,T]
{
    __shared__ f32x4 sAcc[4][64][8];     // 32 KB

    const int bid = blockIdx.x;          // b*MT_ + mt
    const int b = bid / MT_, mt = bid % MT_;
    const int w = threadIdx.x >> 6, l = threadIdx.x & 63;
    const int ml = l & 15, kg = l >> 4;

    // wave w covers k in [w*256, (w+1)*256)
    const short* Ax = (const short*)xsbuf + ((size_t)(b*2+0)*QPAD_ + mt*16 + ml)*P_ + kg*8 + w*256;
    const short* As = (const short*)xsbuf + ((size_t)(b*2+1)*QPAD_ + mt*16 + ml)*P_ + kg*8 + w*256;
    const short* Bb = (const short*)tgtPT + ((size_t)(b*T_) + ml)*P_ + kg*8 + w*256;

    f32x4 accX[4] = {{0,0,0,0},{0,0,0,0},{0,0,0,0},{0,0,0,0}};
    f32x4 accS[4] = {{0,0,0,0},{0,0,0,0},{0,0,0,0},{0,0,0,0}};

    #pragma unroll
    for (int kt = 0; kt < 8; ++kt) {
        const int ko = kt * 32;
        short8 afx = *(const short8*)(Ax + ko);
        short8 afs = *(const short8*)(As + ko);
        #pragma unroll
        for (int nt = 0; nt < 4; ++nt) {
            short8 bf = *(const short8*)(Bb + (size_t)nt*16*P_ + ko);
            accX[nt] = __builtin_amdgcn_mfma_f32_16x16x32_bf16(afx, bf, accX[nt], 0, 0, 0);
            accS[nt] = __builtin_amdgcn_mfma_f32_16x16x32_bf16(afs, bf, accS[nt], 0, 0, 0);
        }
    }

    #pragma unroll
    for (int nt = 0; nt < 4; ++nt) {
        sAcc[w][l][nt*2+0] = accX[nt];
        sAcc[w][l][nt*2+1] = accS[nt];
    }
    __syncthreads();

    // wave w handles epilogue for nt = w (t = w*16 + ml)
    f32x4 aX = sAcc[0][l][w*2+0];
    f32x4 aS = sAcc[0][l][w*2+1];
    #pragma unroll
    for (int w2 = 1; w2 < 4; ++w2) {
        aX += sAcc[w2][l][w*2+0];
        aS += sAcc[w2][l][w*2+1];
    }

    const int t = w*16 + ml;
    const float tsu = tsum[b*T_ + t];
    const int   lab = tgt_labels[b*T_ + t];
    const float4 tbx = *(const float4*)(tgt_boxes + (size_t)(b*T_ + t)*4);
    float tx1 = tbx.x - 0.5f*tbx.z, ty1 = tbx.y - 0.5f*tbx.w;
    float tx2 = tbx.x + 0.5f*tbx.z, ty2 = tbx.y + 0.5f*tbx.w;
    float a2 = (tx2-tx1)*(ty2-ty1);

    #pragma unroll
    for (int r = 0; r < 4; ++r) {
        int q = mt*16 + kg*4 + r;
        int qc = min(q, Q_-1);
        float ln  = lneg[b*Q_ + qc];
        float lsv = lsum[b*Q_ + qc];
        float4 pb = *(const float4*)(pred_boxes + (size_t)(b*Q_ + qc)*4);
        float lg = pred_logits[((size_t)(b*Q_ + qc))*CC_ + lab];

        float ce   = (ln - aX[r]) * (1.f/(float)P_);
        float dice = 1.f - (2.f*aS[r] + 1.f) / (lsv + tsu + 1.f);

        float e  = __expf(-fabsf(lg));
        float lp = log1pf(e);
        float sp_neg = lp + fmaxf(-lg, 0.f);
        float sp_pos = lp + fmaxf( lg, 0.f);
        float prob = 1.f / (1.f + __expf(-lg));
        float cclass = 0.25f*(1.f-prob)*(1.f-prob)*sp_neg - 0.75f*prob*prob*sp_pos;

        float cbbox = fabsf(pb.x-tbx.x) + fabsf(pb.y-tbx.y) + fabsf(pb.z-tbx.z) + fabsf(pb.w-tbx.w);
        float px1 = pb.x - 0.5f*pb.z, py1 = pb.y - 0.5f*pb.w;
        float px2 = pb.x + 0.5f*pb.z, py2 = pb.y + 0.5f*pb.w;
        float a1 = (px2-px1)*(py2-py1);
        float iw = fmaxf(fminf(px2,tx2) - fmaxf(px1,tx1), 0.f);
        float ih = fmaxf(fminf(py2,ty2) - fmaxf(py1,ty1), 0.f);
        float inter = iw*ih;
        float uni = a1 + a2 - inter;
        float iou = inter / uni;
        float cw = fmaxf(fmaxf(px2,tx2) - fminf(px1,tx1), 0.f);
        float ch = fmaxf(fmaxf(py2,ty2) - fminf(py1,ty1), 0.f);
        float ac = cw*ch;
        float giou = iou - (ac - uni)/ac;

        if (q < Q_)
            out[((size_t)(b*Q_ + q))*T_ + t] = cbbox + cclass - giou + ce + dice;
    }
}

// ---------------- k4: per-batch max of where(finite, C, 0), 64 blocks/batch + atomicMax ----------------
__global__ __launch_bounds__(256) void k4_max(const float* __restrict__ out,
                                              float* __restrict__ bmax)
{
    const int b   = blockIdx.x >> 6;     // 64 blocks per batch
    const int blk = blockIdx.x & 63;
    const float* base = out + (size_t)b * Q_ * T_;
    float m = 0.f;                        // clamp at 0: max only matters when a non-finite exists,
                                          // in which case reference candidates include 0 as well
    for (int i = blk*256 + threadIdx.x; i < Q_*T_; i += 64*256) {
        float v = base[i];
        float c = (fabsf(v) <= FLT_BIG) ? v : 0.f;
        m = fmaxf(m, c);
    }
    #pragma unroll
    for (int off = 32; off; off >>= 1) m = fmaxf(m, __shfl_down(m, off));
    __shared__ float sm[4];
    if ((threadIdx.x & 63) == 0) sm[threadIdx.x >> 6] = m;
    __syncthreads();
    if (threadIdx.x == 0) {
        float bm = fmaxf(fmaxf(sm[0], sm[1]), fmaxf(sm[2], sm[3]));
        atomicMax((unsigned int*)&bmax[b], __float_as_uint(bm));  // bm >= 0: uint order == float order
    }
}

// ---------------- k5: replace non-finite with 2*max ----------------
__global__ __launch_bounds__(256) void k5_fix(float* __restrict__ out,
                                              const float* __restrict__ bmax)
{
    int i = blockIdx.x*256 + threadIdx.x;
    if (i >= B_*Q_*T_) return;
    float v = out[i];
    if (!(fabsf(v) <= FLT_BIG))
        out[i] = 2.f * bmax[i / (Q_*T_)];
}

extern "C" void kernel_launch(void* const* d_in, const int* in_sizes, int n_in,
                              void* d_out, int out_size, void* d_ws, size_t ws_size,
                              hipStream_t stream) {
    const float* pred_logits  = (const float*)d_in[0];
    const float* pred_boxes   = (const float*)d_in[1];
    const float* pred_masks   = (const float*)d_in[2];
    const float* tgt_boxes    = (const float*)d_in[3];
    const float* tgt_masks    = (const float*)d_in[4];
    const float* point_coords = (const float*)d_in[5];
    const int*   tgt_labels   = (const int*)d_in[6];
    float* out = (float*)d_out;

    // workspace layout (16B-aligned), total ~7.8 MB
    char* w = (char*)d_ws;
    int4*           offs  = (int4*)w;                                   // 16 KB
    float4*         wts   = (float4*)(w + 16384);                       // 16 KB
    unsigned short* tgtPT = (unsigned short*)(w + 32768);               // 256 KB
    unsigned short* xsbuf = (unsigned short*)(w + 32768 + 262144);      // 7.29 MB
    size_t xs_bytes = (size_t)B_*2*QPAD_*P_*2;
    char* w2 = w + 32768 + 262144 + xs_bytes;
    float* tsum = (float*)w2;                    // 512 B
    float* lneg = (float*)(w2 + 512);            // 7200 B (pad to 7296)
    float* lsum = (float*)(w2 + 512 + 7296);     // 7200 B
    float* bmax = (float*)(w2 + 512 + 2*7296);

    k1_prep<<<B_*T_, 256, 0, stream>>>(tgt_masks, point_coords, offs, wts, tgtPT, tsum, bmax);
    k2_sample<<<B_*Q_, 256, 0, stream>>>(pred_masks, offs, wts, xsbuf, lneg, lsum);
    k3_gemm<<<B_*MT_, 256, 0, stream>>>(xsbuf, tgtPT, lneg, lsum, tsum,
                                        pred_logits, pred_boxes, tgt_boxes, tgt_labels, out);
    k4_max<<<B_*64, 256, 0, stream>>>(out, bmax);
    k5_fix<<<(B_*Q_*T_ + 255)/256, 256, 0, stream>>>(out, bmax);
}